// Round 13
// baseline (186.993 us; speedup 1.0000x reference)
//
#include <hip/hip_runtime.h>

#define BB 256
#define TT 256
#define CC 256
#define HH 64

typedef _Float16 half8 __attribute__((ext_vector_type(8)));
typedef _Float16 half4 __attribute__((ext_vector_type(4)));
typedef __fp16 fp16x2 __attribute__((ext_vector_type(2)));
typedef float floatx4 __attribute__((ext_vector_type(4)));

// ---------------------------------------------------------------------------
// fused: one block per batch b, 512 threads, LDS = 67.6 KB -> 2 blocks/CU
// (r12 post-mortem: 132.9 KB LDS -> 1 block/CU -> 8 waves = latency-bound;
//  throughput costs sum to ~30us of the 58us measured).
//   phase 1: proj in TWO K-chunks: stage W[*, k-chunk] (f16, stride 136 pad)
//            into LDS (52.2 KB, aliased with weih), MFMA, repeat.  q/k/vT ->
//            ws (block-local, L2-hot).  K pre-scaled 0.125.
//   phase 2: flash, identical structure to r12; rpe B-frags now read f32
//            from global (L2-hot 65 KB) + cvt_pkrtz instead of LDS.
// ---------------------------------------------------------------------------
__global__ __launch_bounds__(512, 4) void fused(
    const float* __restrict__ x,
    const float* __restrict__ Wk, const float* __restrict__ Wq, const float* __restrict__ Wv,
    const float* __restrict__ rpe,
    _Float16* __restrict__ qh, _Float16* __restrict__ kh, _Float16* __restrict__ vTh,
    float* __restrict__ out)
{
    __shared__ __align__(16) unsigned char ldsbuf[8 * 16 * 264 * 2]; // 67.6 KB
    _Float16* wt = (_Float16*)ldsbuf;           // [192][136] per k-chunk (52.2 KB)

    const int tid  = threadIdx.x;
    const int b    = blockIdx.x;
    const int w    = tid >> 6;
    const int lane = tid & 63;
    const int quad = lane >> 4;
    const int l    = lane & 15;

    union H8 { half8 v; fp16x2 p[4]; };
    const float* Ws[3] = {Wk, Wq, Wv};
    const float4* xg = reinterpret_cast<const float4*>(x);

    // ---- phase 1: proj in 2 k-chunks, 8 waves x 32 rows ------------------
    const int row0 = b * 256 + w * 32;
    floatx4 acc[12][2];
#pragma unroll
    for (int nt = 0; nt < 12; ++nt)
#pragma unroll
        for (int rt = 0; rt < 2; ++rt) acc[nt][rt] = (floatx4){0.f, 0.f, 0.f, 0.f};

#pragma unroll
    for (int c = 0; c < 2; ++c) {
        // stage W k-chunk c: [192 rows][128 k] f32 -> f16 LDS stride 136
#pragma unroll
        for (int wsel = 0; wsel < 3; ++wsel) {
            const float4* W4 = reinterpret_cast<const float4*>(Ws[wsel]);
#pragma unroll
            for (int j = 0; j < 4; ++j) {
                const int f4   = tid + j * 512;          // 0..2047
                const int kloc = f4 >> 4;                // 0..127
                const int n0   = (f4 & 15) * 4;
                const float4 v = W4[(size_t)(c * 128 + kloc) * 16 + (f4 & 15)];
#pragma unroll
                for (int e = 0; e < 4; ++e)
                    wt[(wsel * 64 + n0 + e) * 136 + kloc] = (_Float16)((&v.x)[e]);
            }
        }
        __syncthreads();

#pragma unroll
        for (int kk = 0; kk < 4; ++kk) {
            const size_t base0 = (size_t)(row0 + l) * 64 + c * 32 + kk * 8 + quad * 2;
            const size_t base1 = base0 + 16 * 64;
            const float4 a0lo = xg[base0], a0hi = xg[base0 + 1];
            const float4 a1lo = xg[base1], a1hi = xg[base1 + 1];
            H8 u0, u1;
            u0.p[0] = __builtin_amdgcn_cvt_pkrtz(a0lo.x, a0lo.y);
            u0.p[1] = __builtin_amdgcn_cvt_pkrtz(a0lo.z, a0lo.w);
            u0.p[2] = __builtin_amdgcn_cvt_pkrtz(a0hi.x, a0hi.y);
            u0.p[3] = __builtin_amdgcn_cvt_pkrtz(a0hi.z, a0hi.w);
            u1.p[0] = __builtin_amdgcn_cvt_pkrtz(a1lo.x, a1lo.y);
            u1.p[1] = __builtin_amdgcn_cvt_pkrtz(a1lo.z, a1lo.w);
            u1.p[2] = __builtin_amdgcn_cvt_pkrtz(a1hi.x, a1hi.y);
            u1.p[3] = __builtin_amdgcn_cvt_pkrtz(a1hi.z, a1hi.w);

#pragma unroll
            for (int nt = 0; nt < 12; ++nt) {
                const half8 bf = *(const half8*)&wt[(nt * 16 + l) * 136 + kk * 32 + quad * 8];
                acc[nt][0] = __builtin_amdgcn_mfma_f32_16x16x32_f16(u0.v, bf, acc[nt][0], 0, 0, 0);
                acc[nt][1] = __builtin_amdgcn_mfma_f32_16x16x32_f16(u1.v, bf, acc[nt][1], 0, 0, 0);
            }
        }
        __syncthreads();   // chunk done (also protects restage / weih alias)
    }

    // epilogue: q/k (pre-scaled) row-major, v transposed
    {
        const int trw = w * 32;
#pragma unroll
        for (int nt = 0; nt < 4; ++nt) {
#pragma unroll
            for (int rt = 0; rt < 2; ++rt) {
#pragma unroll
                for (int r = 0; r < 4; ++r) {
                    const size_t row = (size_t)row0 + rt * 16 + quad * 4 + r;
                    kh[row * HH + nt * 16 + l] = (_Float16)(acc[nt][rt][r] * 0.125f);
                    qh[row * HH + nt * 16 + l] = (_Float16)acc[nt + 4][rt][r];
                }
                half4 vv;
                vv[0] = (_Float16)acc[nt + 8][rt][0];
                vv[1] = (_Float16)acc[nt + 8][rt][1];
                vv[2] = (_Float16)acc[nt + 8][rt][2];
                vv[3] = (_Float16)acc[nt + 8][rt][3];
                *(half4*)(vTh + ((size_t)b * HH + nt * 16 + l) * TT + trw + rt * 16 + quad * 4) = vv;
            }
        }
    }
    __syncthreads();   // q/k/vT of batch b visible block-wide (vmcnt drain)

    // ---- phase 2: flash, wave w does tiles {w, 15-w}, weih slot w --------
    _Float16* wh = (_Float16*)ldsbuf + w * (16 * 264);
    const float4* rp4 = reinterpret_cast<const float4*>(rpe);

#pragma unroll
    for (int pass = 0; pass < 2; ++pass) {
        const int tile  = pass ? (15 - w) : w;
        const int tw    = tile * 16;
        const int stmax = tile;
        const int cmax  = tile >> 1;
        const int dtmin = 15 - tile;

        const _Float16* qp = qh + (size_t)(b * TT + tw + l) * HH + quad * 8;
        const half8 qf0 = *(const half8*)qp;
        const half8 qf1 = *(const half8*)(qp + 32);

        // P-GEMM: rpe f32 from global + cvt, skewed scatter wh[row][s]
#pragma unroll
        for (int dt = 0; dt < 16; ++dt) {
            if (dt >= dtmin) {
                const size_t rb = (size_t)(dt * 16 + l) * 16 + quad * 2;
                const float4 r0lo = rp4[rb],     r0hi = rp4[rb + 1];
                const float4 r1lo = rp4[rb + 8], r1hi = rp4[rb + 9];
                H8 v0, v1;
                v0.p[0] = __builtin_amdgcn_cvt_pkrtz(r0lo.x, r0lo.y);
                v0.p[1] = __builtin_amdgcn_cvt_pkrtz(r0lo.z, r0lo.w);
                v0.p[2] = __builtin_amdgcn_cvt_pkrtz(r0hi.x, r0hi.y);
                v0.p[3] = __builtin_amdgcn_cvt_pkrtz(r0hi.z, r0hi.w);
                v1.p[0] = __builtin_amdgcn_cvt_pkrtz(r1lo.x, r1lo.y);
                v1.p[1] = __builtin_amdgcn_cvt_pkrtz(r1lo.z, r1lo.w);
                v1.p[2] = __builtin_amdgcn_cvt_pkrtz(r1hi.x, r1hi.y);
                v1.p[3] = __builtin_amdgcn_cvt_pkrtz(r1hi.z, r1hi.w);
                floatx4 z = {0.f, 0.f, 0.f, 0.f};
                z = __builtin_amdgcn_mfma_f32_16x16x32_f16(qf0, v0.v, z, 0, 0, 0);
                const floatx4 pacc = __builtin_amdgcn_mfma_f32_16x16x32_f16(qf1, v1.v, z, 0, 0, 0);
                if (dt == dtmin) {
#pragma unroll
                    for (int r = 0; r < 4; ++r) {
                        const int row = quad * 4 + r;
                        const int s   = l + row - 15;
                        if (s >= 0) wh[row * 264 + s] = (_Float16)pacc[r];
                    }
                } else {
#pragma unroll
                    for (int r = 0; r < 4; ++r) {
                        const int row = quad * 4 + r;
                        const int s   = dt * 16 + l + tw + row - 255;
                        wh[row * 264 + s] = (_Float16)pacc[r];
                    }
                }
            }
        }

        // content scores (K pre-scaled 0.125)
        floatx4 sacc[16];
#pragma unroll
        for (int st = 0; st < 16; ++st) {
            if (st <= stmax) {
                const _Float16* kp = kh + (size_t)(b * TT + st * 16 + l) * HH + quad * 8;
                const half8 kf0 = *(const half8*)kp;
                const half8 kf1 = *(const half8*)(kp + 32);
                floatx4 z = {0.f, 0.f, 0.f, 0.f};
                z = __builtin_amdgcn_mfma_f32_16x16x32_f16(qf0, kf0, z, 0, 0, 0);
                sacc[st] = __builtin_amdgcn_mfma_f32_16x16x32_f16(qf1, kf1, z, 0, 0, 0);
            }
        }

        // shiftless softmax
        float sums[4] = {0.f, 0.f, 0.f, 0.f};
#pragma unroll
        for (int st = 0; st < 16; ++st) {
            if (st < stmax) {
                const int s = l + 16 * st;
#pragma unroll
                for (int r = 0; r < 4; ++r) {
                    const int row = quad * 4 + r;
                    const float e = __expf(sacc[st][r] + (float)wh[row * 264 + s]);
                    sums[r] += e;
                    wh[row * 264 + s] = (_Float16)e;
                }
            }
        }
        {   // diagonal tile
            const int s = l + 16 * stmax;
#pragma unroll
            for (int r = 0; r < 4; ++r) {
                const int row = quad * 4 + r;
                float e = 0.f;
                if (l <= row) e = __expf(sacc[stmax][r] + (float)wh[row * 264 + s]);
                sums[r] += e;
                wh[row * 264 + s] = (_Float16)e;
            }
        }
        if ((tile & 1) == 0) {   // zero strip covering the PV read window
            const int s = l + 16 * (stmax + 1);
#pragma unroll
            for (int r = 0; r < 4; ++r) wh[(quad * 4 + r) * 264 + s] = (_Float16)0.f;
        }

        float inv_r[4];
#pragma unroll
        for (int r = 0; r < 4; ++r) {
            float sum = sums[r];
            sum += __shfl_xor(sum, 1);
            sum += __shfl_xor(sum, 2);
            sum += __shfl_xor(sum, 4);
            sum += __shfl_xor(sum, 8);
            inv_r[r] = 1.0f / sum;
        }

        // PV
        floatx4 oacc[4] = {{0.f,0.f,0.f,0.f},{0.f,0.f,0.f,0.f},
                           {0.f,0.f,0.f,0.f},{0.f,0.f,0.f,0.f}};
#pragma unroll
        for (int c = 0; c < 8; ++c) {
            if (c <= cmax) {
                const half8 af = *(const half8*)&wh[l * 264 + c * 32 + quad * 8];
#pragma unroll
                for (int ht = 0; ht < 4; ++ht) {
                    const half8 vf = *(const half8*)(vTh +
                        ((size_t)b * HH + ht * 16 + l) * TT + c * 32 + quad * 8);
                    oacc[ht] = __builtin_amdgcn_mfma_f32_16x16x32_f16(af, vf, oacc[ht], 0, 0, 0);
                }
            }
        }

#pragma unroll
        for (int ht = 0; ht < 4; ++ht) {
#pragma unroll
            for (int r = 0; r < 4; ++r) {
                const int t = tw + quad * 4 + r;
                out[(size_t)(b * TT + t) * HH + ht * 16 + l] = oacc[ht][r] * inv_r[r];
            }
        }
    }
}

extern "C" void kernel_launch(void* const* d_in, const int* in_sizes, int n_in,
                              void* d_out, int out_size, void* d_ws, size_t ws_size,
                              hipStream_t stream) {
    const float* x   = (const float*)d_in[0];
    const float* Wk  = (const float*)d_in[1];
    const float* Wq  = (const float*)d_in[2];
    const float* Wv  = (const float*)d_in[3];
    const float* rpe = (const float*)d_in[4];
    float* out = (float*)d_out;

    const size_t NQ = (size_t)BB * TT * HH;
    _Float16* qh  = (_Float16*)d_ws;
    _Float16* kh  = qh + NQ;
    _Float16* vTh = kh + NQ;

    fused<<<dim3(BB), dim3(512), 0, stream>>>(x, Wk, Wq, Wv, rpe, qh, kh, vTh, out);
}

// Round 14
// 146.003 us; speedup vs baseline: 1.2807x; 1.2807x over previous
//
#include <hip/hip_runtime.h>

#define BB 256
#define TT 256
#define CC 256
#define HH 64

typedef _Float16 half8 __attribute__((ext_vector_type(8)));
typedef _Float16 half4 __attribute__((ext_vector_type(4)));
typedef __fp16 fp16x2 __attribute__((ext_vector_type(2)));
typedef float floatx4 __attribute__((ext_vector_type(4)));

// ---------------------------------------------------------------------------
// prep: blocks 0..63   -> rpeh[i] = (f16) rpe[i]  (rows 0..255)
//       blocks 64..255 -> WT[(w*64+n)][k] = (f16) W_w[k][n]
// ---------------------------------------------------------------------------
__global__ __launch_bounds__(256) void prep(
    const float* __restrict__ rpe,
    const float* __restrict__ Wk, const float* __restrict__ Wq, const float* __restrict__ Wv,
    _Float16* __restrict__ rpeh, _Float16* __restrict__ WT)
{
    const int bid = blockIdx.x, tid = threadIdx.x;
    if (bid < 64) {
        const int i = bid * 256 + tid;
        rpeh[i] = (_Float16)rpe[i];
    } else {
        const int wsel = (bid - 64) >> 6;          // 0=k, 1=q, 2=v
        const int n    = (bid - 64) & 63;
        const float* W = wsel == 0 ? Wk : (wsel == 1 ? Wq : Wv);
        WT[(size_t)(wsel * 64 + n) * 256 + tid] = (_Float16)W[tid * HH + n];
    }
}

// ---------------------------------------------------------------------------
// fused: one block per batch, 1024 threads (16 waves), 1 block/CU.
// r13 post-mortem: 2 blocks/CU blew the per-XCD L2 qkv working set (6.3 MB
// > 4 MB) -> HBM thrash.  This keeps 1 block/CU and doubles waves instead.
//   phase 0: copy WT f16 (96 KB) -> LDS, XOR-granule swizzle (clean copy,
//            no transpose scatter -> conflicts gone vs r12).
//   phase 1: proj, 16 waves x 16 rows, B-frags from LDS.  K pre-scaled.
//   phase 2: flash; wave w -> query tile w (max wave == one r12 wave-pair).
//            weih (16 slots, 135.2 KB) aliases WT.  rpe B-frags from global
//            f16 rpeh (32 KB, L2-hot; NOT r13's fp32+cvt).
// ---------------------------------------------------------------------------
__global__ __launch_bounds__(1024, 4) void fused(
    const float* __restrict__ x, const _Float16* __restrict__ WT,
    const _Float16* __restrict__ rpeh,
    _Float16* __restrict__ qh, _Float16* __restrict__ kh, _Float16* __restrict__ vTh,
    float* __restrict__ out)
{
    __shared__ __align__(16) unsigned char ldsbuf[16 * 16 * 264 * 2]; // 135168 B
    _Float16* wt = (_Float16*)ldsbuf;            // [192][256] swizzled (96 KB)

    const int tid  = threadIdx.x;
    const int b    = blockIdx.x;
    const int w    = tid >> 6;
    const int lane = tid & 63;
    const int quad = lane >> 4;
    const int l    = lane & 15;

    union H8 { half8 v; fp16x2 p[4]; };

    // ---- phase 0: WT -> LDS (contiguous copy, XOR-swizzled granules) -----
#pragma unroll
    for (int i = tid; i < 192 * 32; i += 1024) {
        const int row = i >> 5;
        const int g   = i & 31;
        const int pg  = g ^ (row & 31);
        *(half8*)&wt[row * 256 + pg * 8] = *(const half8*)(WT + (size_t)row * 256 + g * 8);
    }
    __syncthreads();

    // ---- phase 1: proj, 16 waves x 16 rows, K pre-scaled 0.125 -----------
    {
        const int row0 = b * 256 + w * 16;
        floatx4 acc[12];
#pragma unroll
        for (int nt = 0; nt < 12; ++nt) acc[nt] = (floatx4){0.f, 0.f, 0.f, 0.f};

        const float4* xg = reinterpret_cast<const float4*>(x);

#pragma unroll
        for (int kk = 0; kk < 8; ++kk) {
            const size_t base = (size_t)(row0 + l) * 64 + kk * 8 + quad * 2;
            const float4 alo = xg[base], ahi = xg[base + 1];
            H8 u;
            u.p[0] = __builtin_amdgcn_cvt_pkrtz(alo.x, alo.y);
            u.p[1] = __builtin_amdgcn_cvt_pkrtz(alo.z, alo.w);
            u.p[2] = __builtin_amdgcn_cvt_pkrtz(ahi.x, ahi.y);
            u.p[3] = __builtin_amdgcn_cvt_pkrtz(ahi.z, ahi.w);

#pragma unroll
            for (int nt = 0; nt < 12; ++nt) {
                const int row = nt * 16 + l;
                const int pg  = (kk * 4 + quad) ^ (row & 31);
                const half8 bf = *(const half8*)&wt[row * 256 + pg * 8];
                acc[nt] = __builtin_amdgcn_mfma_f32_16x16x32_f16(u.v, bf, acc[nt], 0, 0, 0);
            }
        }

        const int trw = w * 16;
#pragma unroll
        for (int nt = 0; nt < 4; ++nt) {
#pragma unroll
            for (int r = 0; r < 4; ++r) {
                const size_t row = (size_t)row0 + quad * 4 + r;
                kh[row * HH + nt * 16 + l] = (_Float16)(acc[nt][r] * 0.125f);
                qh[row * HH + nt * 16 + l] = (_Float16)acc[nt + 4][r];
            }
            half4 vv;
            vv[0] = (_Float16)acc[nt + 8][0];
            vv[1] = (_Float16)acc[nt + 8][1];
            vv[2] = (_Float16)acc[nt + 8][2];
            vv[3] = (_Float16)acc[nt + 8][3];
            *(half4*)(vTh + ((size_t)b * HH + nt * 16 + l) * TT + trw + quad * 4) = vv;
        }
    }
    __syncthreads();   // qkv visible block-wide; weih alias safe

    // ---- phase 2: flash, wave w -> tile w, weih slot w -------------------
    _Float16* wh = (_Float16*)ldsbuf + w * (16 * 264);
    {
        const int tile  = w;
        const int tw    = tile * 16;
        const int stmax = tile;
        const int cmax  = tile >> 1;
        const int dtmin = 15 - tile;

        const _Float16* qp = qh + (size_t)(b * TT + tw + l) * HH + quad * 8;
        const half8 qf0 = *(const half8*)qp;
        const half8 qf1 = *(const half8*)(qp + 32);

        // P-GEMM: rpe f16 from global, skewed scatter wh[row][s]
#pragma unroll
        for (int dt = 0; dt < 16; ++dt) {
            if (dt >= dtmin) {
                const _Float16* rp = rpeh + (size_t)(dt * 16 + l) * HH + quad * 8;
                const half8 bf0 = *(const half8*)rp;
                const half8 bf1 = *(const half8*)(rp + 32);
                floatx4 z = {0.f, 0.f, 0.f, 0.f};
                z = __builtin_amdgcn_mfma_f32_16x16x32_f16(qf0, bf0, z, 0, 0, 0);
                const floatx4 pacc = __builtin_amdgcn_mfma_f32_16x16x32_f16(qf1, bf1, z, 0, 0, 0);
                if (dt == dtmin) {
#pragma unroll
                    for (int r = 0; r < 4; ++r) {
                        const int row = quad * 4 + r;
                        const int s   = l + row - 15;
                        if (s >= 0) wh[row * 264 + s] = (_Float16)pacc[r];
                    }
                } else {
#pragma unroll
                    for (int r = 0; r < 4; ++r) {
                        const int row = quad * 4 + r;
                        const int s   = dt * 16 + l + tw + row - 255;
                        wh[row * 264 + s] = (_Float16)pacc[r];
                    }
                }
            }
        }

        // content scores (K pre-scaled 0.125)
        floatx4 sacc[16];
#pragma unroll
        for (int st = 0; st < 16; ++st) {
            if (st <= stmax) {
                const _Float16* kp = kh + (size_t)(b * TT + st * 16 + l) * HH + quad * 8;
                const half8 kf0 = *(const half8*)kp;
                const half8 kf1 = *(const half8*)(kp + 32);
                floatx4 z = {0.f, 0.f, 0.f, 0.f};
                z = __builtin_amdgcn_mfma_f32_16x16x32_f16(qf0, kf0, z, 0, 0, 0);
                sacc[st] = __builtin_amdgcn_mfma_f32_16x16x32_f16(qf1, kf1, z, 0, 0, 0);
            }
        }

        // shiftless softmax
        float sums[4] = {0.f, 0.f, 0.f, 0.f};
#pragma unroll
        for (int st = 0; st < 16; ++st) {
            if (st < stmax) {
                const int s = l + 16 * st;
#pragma unroll
                for (int r = 0; r < 4; ++r) {
                    const int row = quad * 4 + r;
                    const float e = __expf(sacc[st][r] + (float)wh[row * 264 + s]);
                    sums[r] += e;
                    wh[row * 264 + s] = (_Float16)e;
                }
            }
        }
        {   // diagonal tile
            const int s = l + 16 * stmax;
#pragma unroll
            for (int r = 0; r < 4; ++r) {
                const int row = quad * 4 + r;
                float e = 0.f;
                if (l <= row) e = __expf(sacc[stmax][r] + (float)wh[row * 264 + s]);
                sums[r] += e;
                wh[row * 264 + s] = (_Float16)e;
            }
        }
        if ((tile & 1) == 0) {   // zero strip covering the PV read window
            const int s = l + 16 * (stmax + 1);
#pragma unroll
            for (int r = 0; r < 4; ++r) wh[(quad * 4 + r) * 264 + s] = (_Float16)0.f;
        }

        float inv_r[4];
#pragma unroll
        for (int r = 0; r < 4; ++r) {
            float sum = sums[r];
            sum += __shfl_xor(sum, 1);
            sum += __shfl_xor(sum, 2);
            sum += __shfl_xor(sum, 4);
            sum += __shfl_xor(sum, 8);
            inv_r[r] = 1.0f / sum;
        }

        // PV
        floatx4 oacc[4] = {{0.f,0.f,0.f,0.f},{0.f,0.f,0.f,0.f},
                           {0.f,0.f,0.f,0.f},{0.f,0.f,0.f,0.f}};
#pragma unroll
        for (int c = 0; c < 8; ++c) {
            if (c <= cmax) {
                const half8 af = *(const half8*)&wh[l * 264 + c * 32 + quad * 8];
#pragma unroll
                for (int ht = 0; ht < 4; ++ht) {
                    const half8 vf = *(const half8*)(vTh +
                        ((size_t)b * HH + ht * 16 + l) * TT + c * 32 + quad * 8);
                    oacc[ht] = __builtin_amdgcn_mfma_f32_16x16x32_f16(af, vf, oacc[ht], 0, 0, 0);
                }
            }
        }

#pragma unroll
        for (int ht = 0; ht < 4; ++ht) {
#pragma unroll
            for (int r = 0; r < 4; ++r) {
                const int t = tw + quad * 4 + r;
                out[(size_t)(b * TT + t) * HH + ht * 16 + l] = oacc[ht][r] * inv_r[r];
            }
        }
    }
}

extern "C" void kernel_launch(void* const* d_in, const int* in_sizes, int n_in,
                              void* d_out, int out_size, void* d_ws, size_t ws_size,
                              hipStream_t stream) {
    const float* x   = (const float*)d_in[0];
    const float* Wk  = (const float*)d_in[1];
    const float* Wq  = (const float*)d_in[2];
    const float* Wv  = (const float*)d_in[3];
    const float* rpe = (const float*)d_in[4];
    float* out = (float*)d_out;

    const size_t NQ = (size_t)BB * TT * HH;
    _Float16* qh   = (_Float16*)d_ws;
    _Float16* kh   = qh + NQ;
    _Float16* vTh  = kh + NQ;
    _Float16* rpeh = vTh + NQ;                     // [256][64]
    _Float16* WT   = rpeh + 256 * HH;              // [192][256]

    prep<<<dim3(256), dim3(256), 0, stream>>>(rpe, Wk, Wq, Wv, rpeh, WT);
    fused<<<dim3(BB), dim3(1024), 0, stream>>>(x, WT, rpeh, qh, kh, vTh, out);
}

// Round 15
// 132.312 us; speedup vs baseline: 1.4133x; 1.1035x over previous
//
#include <hip/hip_runtime.h>

#define BB 256
#define TT 256
#define CC 256
#define HH 64

typedef _Float16 half8 __attribute__((ext_vector_type(8)));
typedef _Float16 half4 __attribute__((ext_vector_type(4)));
typedef __fp16 fp16x2 __attribute__((ext_vector_type(2)));
typedef float floatx4 __attribute__((ext_vector_type(4)));

// ---------------------------------------------------------------------------
// prep: blocks 0..63   -> rpeh[i] = (f16) rpe[i]  (rows 0..255)
//       blocks 64..255 -> WT[(w*64+n)][k] = (f16) W_w[k][n]
// ---------------------------------------------------------------------------
__global__ __launch_bounds__(256) void prep(
    const float* __restrict__ rpe,
    const float* __restrict__ Wk, const float* __restrict__ Wq, const float* __restrict__ Wv,
    _Float16* __restrict__ rpeh, _Float16* __restrict__ WT)
{
    const int bid = blockIdx.x, tid = threadIdx.x;
    if (bid < 64) {
        const int i = bid * 256 + tid;
        rpeh[i] = (_Float16)rpe[i];
    } else {
        const int wsel = (bid - 64) >> 6;          // 0=k, 1=q, 2=v
        const int n    = (bid - 64) & 63;
        const float* W = wsel == 0 ? Wk : (wsel == 1 ? Wq : Wv);
        WT[(size_t)(wsel * 64 + n) * 256 + tid] = (_Float16)W[tid * HH + n];
    }
}

// per-wave exp-weight slot pool: pair j = w>>1 shares width V_j
__device__ __forceinline__ int slot_width(int w) {
    const int j = w >> 1;
    return (j < 2) ? 72 : (32 * j + 40);
}
__device__ __forceinline__ int slot_off(int w) {      // halves, rel. to pool
    const int j = w >> 1;
    const int V = (j < 2) ? 72 : (32 * j + 40);
    const int S = (j == 0) ? 0 : (j == 1) ? 72 : (16 * j * j + 24 * j + 32);
    return 32 * S + (w & 1) * 16 * V;
}

// ---------------------------------------------------------------------------
// fused r15: one block per batch, 1024 thr (16 waves), 1 block/CU.
// r14 post-mortem: 58us invariant across r12/r14 = the global qkv round-trip
// (25 MB write + L2 read-back on serialized chains).  Here K/V NEVER leave
// the CU: K->LDS [256][72], VT->LDS [64][264]; q transposes through the
// wave-private slot into registers.  W staged in two 128-K chunks (stride
// 136 = bank-rotated, conflict-free) aliased into the slot pool; x loads
// prefetched 8-deep per chunk (HBM MLP).  Global traffic: x in, out out.
// ---------------------------------------------------------------------------
__global__ __launch_bounds__(1024, 4) void fused(
    const float* __restrict__ x, const _Float16* __restrict__ WT,
    const _Float16* __restrict__ rpeh, float* __restrict__ out)
{
    __shared__ _Float16 lds[75264];        // 147 KB: K | VT | pool
    _Float16* Klds = lds;                  // [256][72]
    _Float16* VT   = lds + 18432;          // [64][264]
    _Float16* pool = lds + 35328;          // 39936 halves (W chunks / slots)

    const int tid  = threadIdx.x;
    const int b    = blockIdx.x;
    const int w    = tid >> 6;
    const int lane = tid & 63;
    const int quad = lane >> 4;
    const int l    = lane & 15;

    union H8 { half8 v; fp16x2 p[4]; };
    const float4* xg = reinterpret_cast<const float4*>(x);
    const int row0g = b * 256 + w * 16;    // wave's 16 x-rows

    floatx4 acc[12];
#pragma unroll
    for (int nt = 0; nt < 12; ++nt) acc[nt] = (floatx4){0.f, 0.f, 0.f, 0.f};

    // ---- phase 1: proj in 2 K-chunks of 128 ------------------------------
#pragma unroll
    for (int c = 0; c < 2; ++c) {
        // stage W chunk c: [192][136] (3072 granules / 1024 thr = 3 each)
#pragma unroll
        for (int i = 0; i < 3; ++i) {
            const int gi  = tid + i * 1024;
            const int row = gi >> 4;
            const int g   = gi & 15;
            *(half8*)&pool[row * 136 + g * 8] =
                *(const half8*)(WT + (size_t)row * 256 + c * 128 + g * 8);
        }
        __syncthreads();

        // prefetch all 8 x float4 for this chunk (MLP), then cvt+MFMA
        float4 xa[4][2];
#pragma unroll
        for (int kk = 0; kk < 4; ++kk) {
            const size_t base = (size_t)(row0g + l) * 64 + c * 32 + kk * 8 + quad * 2;
            xa[kk][0] = xg[base];
            xa[kk][1] = xg[base + 1];
        }
#pragma unroll
        for (int kk = 0; kk < 4; ++kk) {
            H8 u;
            u.p[0] = __builtin_amdgcn_cvt_pkrtz(xa[kk][0].x, xa[kk][0].y);
            u.p[1] = __builtin_amdgcn_cvt_pkrtz(xa[kk][0].z, xa[kk][0].w);
            u.p[2] = __builtin_amdgcn_cvt_pkrtz(xa[kk][1].x, xa[kk][1].y);
            u.p[3] = __builtin_amdgcn_cvt_pkrtz(xa[kk][1].z, xa[kk][1].w);
#pragma unroll
            for (int nt = 0; nt < 12; ++nt) {
                const half8 bf = *(const half8*)&pool[(nt * 16 + l) * 136 + kk * 32 + quad * 8];
                acc[nt] = __builtin_amdgcn_mfma_f32_16x16x32_f16(u.v, bf, acc[nt], 0, 0, 0);
            }
        }
        __syncthreads();   // chunk readers done (protects restage / slots)
    }

    // ---- epilogue: K (scaled) and VT into LDS ----------------------------
    {
        const int trw = w * 16;
#pragma unroll
        for (int nt = 0; nt < 4; ++nt) {
#pragma unroll
            for (int r = 0; r < 4; ++r)
                Klds[(trw + quad * 4 + r) * 72 + nt * 16 + l] = (_Float16)(acc[nt][r] * 0.125f);
            half4 vv;
            vv[0] = (_Float16)acc[nt + 8][0];
            vv[1] = (_Float16)acc[nt + 8][1];
            vv[2] = (_Float16)acc[nt + 8][2];
            vv[3] = (_Float16)acc[nt + 8][3];
            *(half4*)&VT[(nt * 16 + l) * 264 + trw + quad * 4] = vv;
        }
    }
    __syncthreads();       // K/VT visible block-wide; pool free for slots

    // ---- phase 2: flash, wave w -> query tile w --------------------------
    _Float16* wh = pool + slot_off(w);
    const int Vw = slot_width(w);
    const int tile  = w;
    const int tw    = tile * 16;
    const int stmax = tile;
    const int cmax  = tile >> 1;
    const int dtmin = 15 - tile;

    // q: C-layout regs -> own slot -> A-layout regs (wave-local transpose)
    half8 qf0, qf1;
    {
#pragma unroll
        for (int nt = 0; nt < 4; ++nt)
#pragma unroll
            for (int r = 0; r < 4; ++r)
                wh[(quad * 4 + r) * Vw + nt * 16 + l] = (_Float16)acc[nt + 4][r];
        qf0 = *(const half8*)&wh[l * Vw + quad * 8];
        qf1 = *(const half8*)&wh[l * Vw + 32 + quad * 8];
    }

    // P-GEMM: rpe f16 from global (L2-hot), skewed scatter wh[row][s]
#pragma unroll
    for (int dt = 0; dt < 16; ++dt) {
        if (dt >= dtmin) {
            const _Float16* rp = rpeh + (size_t)(dt * 16 + l) * HH + quad * 8;
            const half8 bf0 = *(const half8*)rp;
            const half8 bf1 = *(const half8*)(rp + 32);
            floatx4 z = {0.f, 0.f, 0.f, 0.f};
            z = __builtin_amdgcn_mfma_f32_16x16x32_f16(qf0, bf0, z, 0, 0, 0);
            const floatx4 pacc = __builtin_amdgcn_mfma_f32_16x16x32_f16(qf1, bf1, z, 0, 0, 0);
            if (dt == dtmin) {
#pragma unroll
                for (int r = 0; r < 4; ++r) {
                    const int row = quad * 4 + r;
                    const int s   = l + row - 15;
                    if (s >= 0) wh[row * Vw + s] = (_Float16)pacc[r];
                }
            } else {
#pragma unroll
                for (int r = 0; r < 4; ++r) {
                    const int row = quad * 4 + r;
                    const int s   = dt * 16 + l + tw + row - 255;
                    wh[row * Vw + s] = (_Float16)pacc[r];
                }
            }
        }
    }

    // content scores: K from LDS (pre-scaled 0.125)
    floatx4 sacc[16];
#pragma unroll
    for (int st = 0; st < 16; ++st) {
        if (st <= stmax) {
            const _Float16* kp = &Klds[(st * 16 + l) * 72 + quad * 8];
            const half8 kf0 = *(const half8*)kp;
            const half8 kf1 = *(const half8*)(kp + 32);
            floatx4 z = {0.f, 0.f, 0.f, 0.f};
            z = __builtin_amdgcn_mfma_f32_16x16x32_f16(qf0, kf0, z, 0, 0, 0);
            sacc[st] = __builtin_amdgcn_mfma_f32_16x16x32_f16(qf1, kf1, z, 0, 0, 0);
        }
    }

    // shiftless softmax (scores bounded); diagonal tile masked
    float sums[4] = {0.f, 0.f, 0.f, 0.f};
#pragma unroll
    for (int st = 0; st < 16; ++st) {
        if (st < stmax) {
            const int s = l + 16 * st;
#pragma unroll
            for (int r = 0; r < 4; ++r) {
                const int row = quad * 4 + r;
                const float e = __expf(sacc[st][r] + (float)wh[row * Vw + s]);
                sums[r] += e;
                wh[row * Vw + s] = (_Float16)e;
            }
        }
    }
    {   // diagonal tile
        const int s = l + 16 * stmax;
#pragma unroll
        for (int r = 0; r < 4; ++r) {
            const int row = quad * 4 + r;
            float e = 0.f;
            if (l <= row) e = __expf(sacc[stmax][r] + (float)wh[row * Vw + s]);
            sums[r] += e;
            wh[row * Vw + s] = (_Float16)e;
        }
    }
    if ((tile & 1) == 0) {   // zero strip covering the PV read window
        const int s = l + 16 * (stmax + 1);
#pragma unroll
        for (int r = 0; r < 4; ++r) wh[(quad * 4 + r) * Vw + s] = (_Float16)0.f;
    }

    float inv_r[4];
#pragma unroll
    for (int r = 0; r < 4; ++r) {
        float sum = sums[r];
        sum += __shfl_xor(sum, 1);
        sum += __shfl_xor(sum, 2);
        sum += __shfl_xor(sum, 4);
        sum += __shfl_xor(sum, 8);
        inv_r[r] = 1.0f / sum;
    }

    // PV: A-frags from own slot, B-frags from VT (LDS)
    floatx4 oacc[4] = {{0.f,0.f,0.f,0.f},{0.f,0.f,0.f,0.f},
                       {0.f,0.f,0.f,0.f},{0.f,0.f,0.f,0.f}};
#pragma unroll
    for (int c = 0; c < 8; ++c) {
        if (c <= cmax) {
            const half8 af = *(const half8*)&wh[l * Vw + c * 32 + quad * 8];
#pragma unroll
            for (int ht = 0; ht < 4; ++ht) {
                const half8 vf = *(const half8*)&VT[(ht * 16 + l) * 264 + c * 32 + quad * 8];
                oacc[ht] = __builtin_amdgcn_mfma_f32_16x16x32_f16(af, vf, oacc[ht], 0, 0, 0);
            }
        }
    }

#pragma unroll
    for (int ht = 0; ht < 4; ++ht) {
#pragma unroll
        for (int r = 0; r < 4; ++r) {
            const int t = tw + quad * 4 + r;
            out[(size_t)(b * TT + t) * HH + ht * 16 + l] = oacc[ht][r] * inv_r[r];
        }
    }
}

extern "C" void kernel_launch(void* const* d_in, const int* in_sizes, int n_in,
                              void* d_out, int out_size, void* d_ws, size_t ws_size,
                              hipStream_t stream) {
    const float* x   = (const float*)d_in[0];
    const float* Wk  = (const float*)d_in[1];
    const float* Wq  = (const float*)d_in[2];
    const float* Wv  = (const float*)d_in[3];
    const float* rpe = (const float*)d_in[4];
    float* out = (float*)d_out;

    _Float16* rpeh = (_Float16*)d_ws;              // [256][64]
    _Float16* WT   = rpeh + 256 * HH;              // [192][256]

    prep<<<dim3(256), dim3(256), 0, stream>>>(rpe, Wk, Wq, Wv, rpeh, WT);
    fused<<<dim3(BB), dim3(1024), 0, stream>>>(x, WT, rpeh, out);
}